// Round 7
// baseline (519.227 us; speedup 1.0000x reference)
//
#include <hip/hip_runtime.h>
#include <math.h>

// Problem dims
#define NB 64
#define NT 1280
#define NP 1024
#define NF 256
#define ND 256

typedef __attribute__((ext_vector_type(8))) short bf16x8;
typedef __attribute__((ext_vector_type(4))) float f32x4;

static __device__ __forceinline__ short f2bf(float f) {
    unsigned u = __float_as_uint(f);
    unsigned r = (u + 0x7fffu + ((u >> 16) & 1u)) >> 16;
    return (short)r;
}
static __device__ __forceinline__ float bf2f(short s) {
    return __uint_as_float(((unsigned)(unsigned short)s) << 16);
}

// ---------------- theta = W @ W^T (256x256x256) ----------------
__global__ __launch_bounds__(256) void theta_kernel(const float* __restrict__ W,
                                                    float* __restrict__ theta) {
    __shared__ __align__(16) float As[64][68];
    __shared__ __align__(16) float BsT[64][65];
    int tid = threadIdx.x;
    int ib = blockIdx.x * 64, jb = blockIdx.y * 64;
    int ty = tid >> 4, tx4 = (tid & 15) * 4;
    float acc[4][4] = {};
    for (int kb = 0; kb < 256; kb += 64) {
        #pragma unroll
        for (int i = 0; i < 4; ++i) {
            int e = tid * 4 + i * 1024;
            int r = e >> 6, c = e & 63;
            *(float4*)&As[r][c] = *(const float4*)(W + (size_t)(ib + r) * 256 + kb + c);
            float4 bv = *(const float4*)(W + (size_t)(jb + r) * 256 + kb + c);
            BsT[c + 0][r] = bv.x; BsT[c + 1][r] = bv.y;
            BsT[c + 2][r] = bv.z; BsT[c + 3][r] = bv.w;
        }
        __syncthreads();
        #pragma unroll
        for (int k = 0; k < 64; ++k) {
            float a[4], b[4];
            #pragma unroll
            for (int i = 0; i < 4; ++i) a[i] = As[ty * 4 + i][k];
            #pragma unroll
            for (int j = 0; j < 4; ++j) b[j] = BsT[k][tx4 + j];
            #pragma unroll
            for (int i = 0; i < 4; ++i)
                #pragma unroll
                for (int j = 0; j < 4; ++j) acc[i][j] += a[i] * b[j];
        }
        __syncthreads();
    }
    #pragma unroll
    for (int i = 0; i < 4; ++i) {
        float4 o = make_float4(acc[i][0], acc[i][1], acc[i][2], acc[i][3]);
        *(float4*)(theta + (size_t)(ib + ty * 4 + i) * 256 + jb + tx4) = o;
    }
}

// ---------------- mask[f][p] ----------------
__global__ __launch_bounds__(256) void mask_kernel(const float* __restrict__ A,
                                                   float* __restrict__ maskf) {
    int f = blockIdx.x;
    int tid = threadIdx.x;
    const float* row = A + (size_t)(NP + f) * NT;
    float4 v = *(const float4*)(row + tid * 4);
    float vals[4] = {v.x, v.y, v.z, v.w};
    float m = -1e30f;
    #pragma unroll
    for (int i = 0; i < 4; ++i)
        if (vals[i] != 0.f) m = fmaxf(m, vals[i]);
    __shared__ float red[256];
    red[tid] = m;
    __syncthreads();
    for (int s = 128; s > 0; s >>= 1) {
        if (tid < s) red[tid] = fmaxf(red[tid], red[tid + s]);
        __syncthreads();
    }
    m = red[0];
    __syncthreads();
    float e[4];
    float sloc = 0.f;
    #pragma unroll
    for (int i = 0; i < 4; ++i) {
        e[i] = (vals[i] != 0.f) ? expf(vals[i] - m) : 0.f;
        sloc += e[i];
    }
    red[tid] = sloc;
    __syncthreads();
    for (int s = 128; s > 0; s >>= 1) {
        if (tid < s) red[tid] += red[tid + s];
        __syncthreads();
    }
    float inv = 1.f / red[0];
    float4 o;
    o.x = (e[0] * inv >= 0.004f) ? 1.f : 0.f;
    o.y = (e[1] * inv >= 0.004f) ? 1.f : 0.f;
    o.z = (e[2] * inv >= 0.004f) ? 1.f : 0.f;
    o.w = (e[3] * inv >= 0.004f) ? 1.f : 0.f;
    *(float4*)(maskf + (size_t)f * NP + tid * 4) = o;
}

// ------- txgemm: TX = x(81920x256) @ theta(256x256) — round-2 structure -------
__global__ __launch_bounds__(256) void txgemm_kernel(const float* __restrict__ A,
                                                     const float* __restrict__ B,
                                                     float* __restrict__ C) {
    __shared__ __align__(16) float As[32][132];   // As[k][r]
    __shared__ __align__(16) float Bs[32][128];   // Bs[k][c]
    int tid = threadIdx.x;
    int cb = blockIdx.x * 128, rb = blockIdx.y * 128;
    int tx = tid & 15, ty = tid >> 4;
    int sr = tid >> 3, sc = (tid & 7) * 4;
    int br = tid >> 5, bc = (tid & 31) * 4;
    float acc[8][8] = {};
    for (int kb = 0; kb < 256; kb += 32) {
        #pragma unroll
        for (int pass = 0; pass < 4; ++pass) {
            int r = sr + pass * 32;
            float4 g = *(const float4*)(A + (size_t)(rb + r) * 256 + kb + sc);
            As[sc + 0][r] = g.x; As[sc + 1][r] = g.y;
            As[sc + 2][r] = g.z; As[sc + 3][r] = g.w;
        }
        #pragma unroll
        for (int pass = 0; pass < 4; ++pass) {
            int r = br + pass * 8;
            *(float4*)&Bs[r][bc] = *(const float4*)(B + (size_t)(kb + r) * 256 + cb + bc);
        }
        __syncthreads();
        #pragma unroll
        for (int k = 0; k < 32; ++k) {
            float4 a0 = *(const float4*)&As[k][ty * 4];
            float4 a1 = *(const float4*)&As[k][64 + ty * 4];
            float4 b0 = *(const float4*)&Bs[k][tx * 4];
            float4 b1 = *(const float4*)&Bs[k][64 + tx * 4];
            float a[8] = {a0.x, a0.y, a0.z, a0.w, a1.x, a1.y, a1.z, a1.w};
            float b[8] = {b0.x, b0.y, b0.z, b0.w, b1.x, b1.y, b1.z, b1.w};
            #pragma unroll
            for (int i = 0; i < 8; ++i)
                #pragma unroll
                for (int j = 0; j < 8; ++j) acc[i][j] += a[i] * b[j];
        }
        __syncthreads();
    }
    #pragma unroll
    for (int i = 0; i < 8; ++i) {
        int row = rb + (i < 4 ? ty * 4 + i : 64 + ty * 4 + i - 4);
        float4 o0 = make_float4(acc[i][0], acc[i][1], acc[i][2], acc[i][3]);
        float4 o1 = make_float4(acc[i][4], acc[i][5], acc[i][6], acc[i][7]);
        *(float4*)(C + (size_t)row * 256 + cb + tx * 4) = o0;
        *(float4*)(C + (size_t)row * 256 + cb + 64 + tx * 4) = o1;
    }
}

// ---------------- q[row] = dot(X[row], TX[row]) ----------------
__global__ __launch_bounds__(256) void q_kernel(const float* __restrict__ X,
                                                const float* __restrict__ TX,
                                                float* __restrict__ q) {
    int row = blockIdx.x * 4 + (threadIdx.x >> 6);
    int lane = threadIdx.x & 63;
    float4 a = *(const float4*)(X + (size_t)row * 256 + lane * 4);
    float4 b = *(const float4*)(TX + (size_t)row * 256 + lane * 4);
    float d = a.x * b.x + a.y * b.y + a.z * b.z + a.w * b.w;
    #pragma unroll
    for (int off = 32; off > 0; off >>= 1) d += __shfl_down(d, off, 64);
    if (lane == 0) q[row] = d;
}

// ------- fused logits + column(f) softmax -> bf16 hi/lo weights (round-2 body) -------
__global__ __launch_bounds__(256) void logits_fused_kernel(const float* __restrict__ x,
                                                           const float* __restrict__ txg,
                                                           const float* __restrict__ q,
                                                           const float* __restrict__ maskf,
                                                           const float* __restrict__ sm,
                                                           short* __restrict__ Whp,
                                                           short* __restrict__ Wlp) {
    __shared__ __align__(16) float Af[32][260];   // [k][f]
    __shared__ __align__(16) float Bp[32][68];    // [k][p]
    __shared__ __align__(16) float red[16][68];
    __shared__ float colM_s[64], colR_s[64];
    __shared__ float qf_s[256], qp_s[64];
    int tid = threadIdx.x;
    int b = blockIdx.y;
    int pb = blockIdx.x * 64;
    int tx = tid & 15, ty = tid >> 4;
    const float* Xf = x + (size_t)b * NT * ND + (size_t)NP * ND;
    const float* Txb = txg + (size_t)b * NT * ND;
    qf_s[tid] = q[b * NT + NP + tid];
    if (tid < 64) qp_s[tid] = q[b * NT + pb + tid];
    int sr = tid >> 3, sc = (tid & 7) * 4;
    float acc[16][4] = {};
    for (int kb = 0; kb < 256; kb += 32) {
        #pragma unroll
        for (int pass = 0; pass < 8; ++pass) {
            int r = sr + pass * 32;
            float4 g = *(const float4*)(Xf + (size_t)r * 256 + kb + sc);
            Af[sc + 0][r] = g.x; Af[sc + 1][r] = g.y;
            Af[sc + 2][r] = g.z; Af[sc + 3][r] = g.w;
        }
        #pragma unroll
        for (int pass = 0; pass < 2; ++pass) {
            int r = sr + pass * 32;
            float4 g = *(const float4*)(Txb + (size_t)(pb + r) * 256 + kb + sc);
            Bp[sc + 0][r] = g.x; Bp[sc + 1][r] = g.y;
            Bp[sc + 2][r] = g.z; Bp[sc + 3][r] = g.w;
        }
        __syncthreads();
        #pragma unroll
        for (int k = 0; k < 32; ++k) {
            float4 bv = *(const float4*)&Bp[k][tx * 4];
            float bj[4] = {bv.x, bv.y, bv.z, bv.w};
            #pragma unroll
            for (int s = 0; s < 4; ++s) {
                float4 av = *(const float4*)&Af[k][s * 64 + ty * 4];
                float ai[4] = {av.x, av.y, av.z, av.w};
                #pragma unroll
                for (int i = 0; i < 4; ++i)
                    #pragma unroll
                    for (int j = 0; j < 4; ++j) acc[s * 4 + i][j] += ai[i] * bj[j];
            }
        }
        __syncthreads();
    }
    float sg = 1.f / (1.f + expf(-sm[0]));
    float cc = 0.5f / (sg * 0.01f);
    #pragma unroll
    for (int s = 0; s < 4; ++s)
        #pragma unroll
        for (int i = 0; i < 4; ++i) {
            int f = s * 64 + ty * 4 + i;
            float qf = qf_s[f];
            float4 mv = *(const float4*)(maskf + (size_t)f * NP + pb + tx * 4);
            float mm[4] = {mv.x, mv.y, mv.z, mv.w};
            #pragma unroll
            for (int j = 0; j < 4; ++j) {
                float qp = qp_s[tx * 4 + j];
                float v = cc * (2.f * acc[s * 4 + i][j] - qf - qp);
                acc[s * 4 + i][j] = (mm[j] != 0.f) ? v : -1e30f;
            }
        }
    // column max over f
    float lm[4] = {-1e30f, -1e30f, -1e30f, -1e30f};
    #pragma unroll
    for (int r = 0; r < 16; ++r)
        #pragma unroll
        for (int j = 0; j < 4; ++j) lm[j] = fmaxf(lm[j], acc[r][j]);
    __syncthreads();
    *(float4*)&red[ty][tx * 4] = make_float4(lm[0], lm[1], lm[2], lm[3]);
    __syncthreads();
    if (tid < 64) {
        float m = -1e30f;
        #pragma unroll
        for (int t = 0; t < 16; ++t) m = fmaxf(m, red[t][tid]);
        colM_s[tid] = m;
    }
    __syncthreads();
    // column sum of exp
    float ls[4] = {0.f, 0.f, 0.f, 0.f};
    #pragma unroll
    for (int j = 0; j < 4; ++j) {
        float m = colM_s[tx * 4 + j];
        #pragma unroll
        for (int r = 0; r < 16; ++r) ls[j] += __expf(acc[r][j] - m);
    }
    __syncthreads();
    *(float4*)&red[ty][tx * 4] = make_float4(ls[0], ls[1], ls[2], ls[3]);
    __syncthreads();
    if (tid < 64) {
        float ssum = 0.f;
        #pragma unroll
        for (int t = 0; t < 16; ++t) ssum += red[t][tid];
        colR_s[tid] = (colM_s[tid] <= -1e29f) ? 0.f : 1.f / ssum;
    }
    __syncthreads();
    // normalized weights -> bf16 hi + lo planes
    #pragma unroll
    for (int s = 0; s < 4; ++s)
        #pragma unroll
        for (int i = 0; i < 4; ++i) {
            int f = s * 64 + ty * 4 + i;
            short4 ph, pl;
            float wv[4];
            #pragma unroll
            for (int j = 0; j < 4; ++j) {
                float m = colM_s[tx * 4 + j];
                float r = colR_s[tx * 4 + j];
                wv[j] = __expf(acc[s * 4 + i][j] - m) * r;
            }
            ph.x = f2bf(wv[0]); ph.y = f2bf(wv[1]); ph.z = f2bf(wv[2]); ph.w = f2bf(wv[3]);
            pl.x = f2bf(wv[0] - bf2f(ph.x));
            pl.y = f2bf(wv[1] - bf2f(ph.y));
            pl.z = f2bf(wv[2] - bf2f(ph.z));
            pl.w = f2bf(wv[3] - bf2f(ph.w));
            size_t off = (size_t)b * NF * NP + (size_t)f * NP + pb + tx * 4;
            *(short4*)(Whp + off) = ph;
            *(short4*)(Wlp + off) = pl;
        }
}

// ------- y transpose + bf16 hi/lo split: yT[b][d][p] -------
__global__ __launch_bounds__(256) void ytr_kernel(const float* __restrict__ y,
                                                  short* __restrict__ Yh,
                                                  short* __restrict__ Yl) {
    __shared__ __align__(16) float T[64][65];
    int b = blockIdx.z;
    int p0 = blockIdx.x * 64, d0 = blockIdx.y * 64;
    int tid = threadIdx.x;
    int r = tid >> 4, c4 = (tid & 15) * 4;
    const float* yb = y + ((size_t)b * NP + p0) * ND + d0;
    #pragma unroll
    for (int pass = 0; pass < 4; ++pass) {
        int row = pass * 16 + r;
        *(float4*)&T[row][c4] = *(const float4*)(yb + (size_t)row * ND + c4);
    }
    __syncthreads();
    short* oh = Yh + ((size_t)b * ND + d0) * NP + p0;
    short* ol = Yl + ((size_t)b * ND + d0) * NP + p0;
    #pragma unroll
    for (int pass = 0; pass < 4; ++pass) {
        int dr = pass * 16 + r;
        short4 hh, ll;
        float v0 = T[c4 + 0][dr], v1 = T[c4 + 1][dr], v2 = T[c4 + 2][dr], v3 = T[c4 + 3][dr];
        hh.x = f2bf(v0); hh.y = f2bf(v1); hh.z = f2bf(v2); hh.w = f2bf(v3);
        ll.x = f2bf(v0 - bf2f(hh.x));
        ll.y = f2bf(v1 - bf2f(hh.y));
        ll.z = f2bf(v2 - bf2f(hh.z));
        ll.w = f2bf(v3 - bf2f(hh.w));
        *(short4*)(oh + (size_t)dr * NP + c4) = hh;
        *(short4*)(ol + (size_t)dr * NP + c4) = ll;
    }
}

// ------- out[b] = W(256x1024) @ y(1024x256) via bf16 MFMA, 3-product split -------
// 64x64 tile, BK=64, 4 waves (2x2 of 32x32), XOR-swizzled LDS, grid (4,4,64)
__global__ __launch_bounds__(256) void out_mfma64_kernel(const short* __restrict__ Whp,
                                                         const short* __restrict__ Wlp,
                                                         const short* __restrict__ Yhp,
                                                         const short* __restrict__ Ylp,
                                                         float* __restrict__ out) {
    __shared__ __align__(16) short Ah[64 * 64];
    __shared__ __align__(16) short Al[64 * 64];
    __shared__ __align__(16) short Bh[64 * 64];
    __shared__ __align__(16) short Bl[64 * 64];
    int tid = threadIdx.x;
    int b = blockIdx.z;
    int db = blockIdx.x * 64, fb = blockIdx.y * 64;
    int l = tid & 63, wave = tid >> 6;
    int wr = wave >> 1, wc = wave & 1;
    int lm = l & 15, kg = l >> 4;
    int srow = tid >> 2, sc16 = tid & 3;   // 64 rows x 8 chunks; each thread 2 chunks
    const short* gA_h = Whp + ((size_t)b * NF + fb) * NP;
    const short* gA_l = Wlp + ((size_t)b * NF + fb) * NP;
    const short* gB_h = Yhp + ((size_t)b * ND + db) * NP;
    const short* gB_l = Ylp + ((size_t)b * ND + db) * NP;
    uint4 ra[4], rbv[4];
#define OIDX(row, c16) ((row) * 64 + ((((c16) ^ ((row) & 7))) << 3))
#define OLOAD(kt) do { \
    _Pragma("unroll") for (int p_ = 0; p_ < 2; ++p_) { \
        size_t go = (size_t)srow * NP + (size_t)(kt) * 64 + (sc16 + p_ * 4) * 8; \
        ra[p_]      = *(const uint4*)(gA_h + go); \
        ra[p_ + 2]  = *(const uint4*)(gA_l + go); \
        rbv[p_]     = *(const uint4*)(gB_h + go); \
        rbv[p_ + 2] = *(const uint4*)(gB_l + go); \
    } \
} while (0)
#define OWRITE() do { \
    _Pragma("unroll") for (int p_ = 0; p_ < 2; ++p_) { \
        int ix = OIDX(srow, sc16 + p_ * 4); \
        *(uint4*)&Ah[ix] = ra[p_];      *(uint4*)&Al[ix] = ra[p_ + 2]; \
        *(uint4*)&Bh[ix] = rbv[p_];     *(uint4*)&Bl[ix] = rbv[p_ + 2]; \
    } \
} while (0)
    f32x4 acc[2][2];
    #pragma unroll
    for (int i = 0; i < 2; ++i)
        #pragma unroll
        for (int j = 0; j < 2; ++j) acc[i][j] = (f32x4){0.f, 0.f, 0.f, 0.f};
    OLOAD(0);
    OWRITE();
    for (int kt = 0; kt < 16; ++kt) {
        __syncthreads();
        bool more = (kt + 1) < 16;
        if (more) OLOAD(kt + 1);
        #pragma unroll
        for (int ks = 0; ks < 2; ++ks) {
            bf16x8 a_h[2], a_l[2], b_h[2], b_l[2];
            #pragma unroll
            for (int mf = 0; mf < 2; ++mf) {
                int row = wr * 32 + mf * 16 + lm;
                int ix = OIDX(row, ks * 4 + kg);
                a_h[mf] = *(const bf16x8*)&Ah[ix];
                a_l[mf] = *(const bf16x8*)&Al[ix];
            }
            #pragma unroll
            for (int nf = 0; nf < 2; ++nf) {
                int row = wc * 32 + nf * 16 + lm;
                int ix = OIDX(row, ks * 4 + kg);
                b_h[nf] = *(const bf16x8*)&Bh[ix];
                b_l[nf] = *(const bf16x8*)&Bl[ix];
            }
            #pragma unroll
            for (int mf = 0; mf < 2; ++mf)
                #pragma unroll
                for (int nf = 0; nf < 2; ++nf) {
                    acc[mf][nf] = __builtin_amdgcn_mfma_f32_16x16x32_bf16(a_h[mf], b_h[nf], acc[mf][nf], 0, 0, 0);
                    acc[mf][nf] = __builtin_amdgcn_mfma_f32_16x16x32_bf16(a_h[mf], b_l[nf], acc[mf][nf], 0, 0, 0);
                    acc[mf][nf] = __builtin_amdgcn_mfma_f32_16x16x32_bf16(a_l[mf], b_h[nf], acc[mf][nf], 0, 0, 0);
                }
        }
        if (!more) break;
        __syncthreads();
        OWRITE();
    }
#undef OIDX
#undef OLOAD
#undef OWRITE
    #pragma unroll
    for (int mf = 0; mf < 2; ++mf) {
        int grow = fb + wr * 32 + mf * 16 + kg * 4;
        #pragma unroll
        for (int nf = 0; nf < 2; ++nf) {
            int gcol = db + wc * 32 + nf * 16 + lm;
            float* op = out + ((size_t)b * NF + grow) * ND + gcol;
            #pragma unroll
            for (int r = 0; r < 4; ++r) op[(size_t)r * ND] = acc[mf][nf][r];
        }
    }
}

extern "C" void kernel_launch(void* const* d_in, const int* in_sizes, int n_in,
                              void* d_out, int out_size, void* d_ws, size_t ws_size,
                              hipStream_t stream) {
    const float* x = (const float*)d_in[0];
    const float* y = (const float*)d_in[1];
    const float* A = (const float*)d_in[2];
    const float* W = (const float*)d_in[3];
    const float* sm = (const float*)d_in[4];
    float* out = (float*)d_out;

    float* ws = (float*)d_ws;
    float* theta = ws;                                  // 65,536 f
    float* maskf = theta + 256 * 256;                   // 262,144 f
    float* q = maskf + 256 * 1024;                      // 81,920 f
    float* tx = q + 64 * 1280;                          // 20,971,520 f
    short* Wh = (short*)(tx + (size_t)64 * 1280 * 256); // 16,777,216 s
    short* Wl = Wh + (size_t)16777216;                  // 16,777,216 s
    // After logits_fused, tx is dead -> reuse its region for Yh/Yl
    short* Yh = (short*)tx;                             // 16,777,216 s
    short* Yl = Yh + (size_t)16777216;                  // fits inside tx region
    // total ~146 MiB

    theta_kernel<<<dim3(4, 4), 256, 0, stream>>>(W, theta);
    mask_kernel<<<dim3(256), 256, 0, stream>>>(A, maskf);
    txgemm_kernel<<<dim3(2, 640), 256, 0, stream>>>(x, theta, tx);
    q_kernel<<<dim3(81920 / 4), 256, 0, stream>>>(x, tx, q);
    logits_fused_kernel<<<dim3(16, 64), 256, 0, stream>>>(x, tx, q, maskf, sm, Wh, Wl);
    ytr_kernel<<<dim3(16, 4, 64), 256, 0, stream>>>(y, Yh, Yl);
    out_mfma64_kernel<<<dim3(4, 4, 64), 256, 0, stream>>>(Wh, Wl, Yh, Yl, out);
}

// Round 8
// 336.714 us; speedup vs baseline: 1.5420x; 1.5420x over previous
//
#include <hip/hip_runtime.h>
#include <math.h>

// Problem dims
#define NB 64
#define NT 1280
#define NP 1024
#define NF 256
#define ND 256

typedef __attribute__((ext_vector_type(8))) short bf16x8;
typedef __attribute__((ext_vector_type(4))) float f32x4;

static __device__ __forceinline__ short f2bf(float f) {
    unsigned u = __float_as_uint(f);
    unsigned r = (u + 0x7fffu + ((u >> 16) & 1u)) >> 16;
    return (short)r;
}
static __device__ __forceinline__ float bf2f(short s) {
    return __uint_as_float(((unsigned)(unsigned short)s) << 16);
}

// ---------------- theta = W @ W^T -> 3 bf16 planes (th0+th1+th2 ~ theta, err 2^-25) ----------------
__global__ __launch_bounds__(256) void theta_kernel(const float* __restrict__ W,
                                                    short* __restrict__ t0,
                                                    short* __restrict__ t1,
                                                    short* __restrict__ t2) {
    __shared__ __align__(16) float As[64][68];
    __shared__ __align__(16) float BsT[64][65];
    int tid = threadIdx.x;
    int ib = blockIdx.x * 64, jb = blockIdx.y * 64;
    int ty = tid >> 4, tx4 = (tid & 15) * 4;
    float acc[4][4] = {};
    for (int kb = 0; kb < 256; kb += 64) {
        #pragma unroll
        for (int i = 0; i < 4; ++i) {
            int e = tid * 4 + i * 1024;
            int r = e >> 6, c = e & 63;
            *(float4*)&As[r][c] = *(const float4*)(W + (size_t)(ib + r) * 256 + kb + c);
            float4 bv = *(const float4*)(W + (size_t)(jb + r) * 256 + kb + c);
            BsT[c + 0][r] = bv.x; BsT[c + 1][r] = bv.y;
            BsT[c + 2][r] = bv.z; BsT[c + 3][r] = bv.w;
        }
        __syncthreads();
        #pragma unroll
        for (int k = 0; k < 64; ++k) {
            float a[4], b[4];
            #pragma unroll
            for (int i = 0; i < 4; ++i) a[i] = As[ty * 4 + i][k];
            #pragma unroll
            for (int j = 0; j < 4; ++j) b[j] = BsT[k][tx4 + j];
            #pragma unroll
            for (int i = 0; i < 4; ++i)
                #pragma unroll
                for (int j = 0; j < 4; ++j) acc[i][j] += a[i] * b[j];
        }
        __syncthreads();
    }
    #pragma unroll
    for (int i = 0; i < 4; ++i) {
        short4 p0, p1, p2;
        float v, r;
        short s0, s1, s2;
        #define SPLIT(idx, fx, fy)  v = acc[i][idx]; s0 = f2bf(v); r = v - bf2f(s0); \
            s1 = f2bf(r); r -= bf2f(s1); s2 = f2bf(r); p0.fx = s0; p1.fx = s1; p2.fx = s2;
        SPLIT(0, x, x) SPLIT(1, y, y) SPLIT(2, z, z) SPLIT(3, w, w)
        #undef SPLIT
        size_t off = (size_t)(ib + ty * 4 + i) * 256 + jb + tx4;
        *(short4*)(t0 + off) = p0;
        *(short4*)(t1 + off) = p1;
        *(short4*)(t2 + off) = p2;
    }
}

// ---------------- mask[f][p] ----------------
__global__ __launch_bounds__(256) void mask_kernel(const float* __restrict__ A,
                                                   float* __restrict__ maskf) {
    int f = blockIdx.x;
    int tid = threadIdx.x;
    const float* row = A + (size_t)(NP + f) * NT;
    float4 v = *(const float4*)(row + tid * 4);
    float vals[4] = {v.x, v.y, v.z, v.w};
    float m = -1e30f;
    #pragma unroll
    for (int i = 0; i < 4; ++i)
        if (vals[i] != 0.f) m = fmaxf(m, vals[i]);
    __shared__ float red[256];
    red[tid] = m;
    __syncthreads();
    for (int s = 128; s > 0; s >>= 1) {
        if (tid < s) red[tid] = fmaxf(red[tid], red[tid + s]);
        __syncthreads();
    }
    m = red[0];
    __syncthreads();
    float e[4];
    float sloc = 0.f;
    #pragma unroll
    for (int i = 0; i < 4; ++i) {
        e[i] = (vals[i] != 0.f) ? expf(vals[i] - m) : 0.f;
        sloc += e[i];
    }
    red[tid] = sloc;
    __syncthreads();
    for (int s = 128; s > 0; s >>= 1) {
        if (tid < s) red[tid] += red[tid + s];
        __syncthreads();
    }
    float inv = 1.f / red[0];
    float4 o;
    o.x = (e[0] * inv >= 0.004f) ? 1.f : 0.f;
    o.y = (e[1] * inv >= 0.004f) ? 1.f : 0.f;
    o.z = (e[2] * inv >= 0.004f) ? 1.f : 0.f;
    o.w = (e[3] * inv >= 0.004f) ? 1.f : 0.f;
    *(float4*)(maskf + (size_t)f * NP + tid * 4) = o;
}

// ------- tx = x @ theta via 6-product 3-way bf16 split MFMA (fp32-class accuracy) -------
// tile 64(M) x 128(N), BK=64, 4 waves each 64x32, XOR-swizzled LDS. grid (2, 1280)
#define OIDX(row, c16) ((row) * 64 + (((c16) ^ ((row) & 7)) << 3))
__global__ __launch_bounds__(256, 2) void txmfma_kernel(const float* __restrict__ X,
                                                        const short* __restrict__ th0,
                                                        const short* __restrict__ th1,
                                                        const short* __restrict__ th2,
                                                        float* __restrict__ TX) {
    __shared__ __align__(16) short Ap[3][64 * 64];
    __shared__ __align__(16) short Bp[3][128 * 64];
    int tid = threadIdx.x;
    int cb = blockIdx.x * 128;
    int rb = blockIdx.y * 64;
    int l = tid & 63, wave = tid >> 6;
    int lm = l & 15, kg = l >> 4;
    int arow = tid >> 2, akq = tid & 3;
    f32x4 acc[4][2];
    #pragma unroll
    for (int i = 0; i < 4; ++i)
        #pragma unroll
        for (int j = 0; j < 2; ++j) acc[i][j] = (f32x4){0.f, 0.f, 0.f, 0.f};
    for (int kt = 0; kt < 4; ++kt) {
        // stage A: fp32 x -> 3 bf16 planes, swizzled
        const float* xs = X + (size_t)(rb + arow) * 256 + kt * 64 + akq * 16;
        #pragma unroll
        for (int i = 0; i < 4; ++i) {
            float4 g = *(const float4*)(xs + i * 4);
            float v[4] = {g.x, g.y, g.z, g.w};
            short4 q0, q1, q2;
            short s0, s1, s2;
            float r;
            #define CSPLIT(idx, fld) s0 = f2bf(v[idx]); r = v[idx] - bf2f(s0); \
                s1 = f2bf(r); r -= bf2f(s1); s2 = f2bf(r); q0.fld = s0; q1.fld = s1; q2.fld = s2;
            CSPLIT(0, x) CSPLIT(1, y) CSPLIT(2, z) CSPLIT(3, w)
            #undef CSPLIT
            int ko = akq * 16 + i * 4;
            int c16 = ko >> 3, off = ko & 7;
            int ix = arow * 64 + (((c16) ^ (arow & 7)) << 3) + off;
            *(short4*)&Ap[0][ix] = q0;
            *(short4*)&Ap[1][ix] = q1;
            *(short4*)&Ap[2][ix] = q2;
        }
        // stage B: theta planes (bf16 global) -> LDS swizzled; 3072 chunks total
        #pragma unroll
        for (int p = 0; p < 12; ++p) {
            int e = tid + p * 256;
            int pl = e >> 10;
            int rem = e & 1023;
            int col = rem >> 3, c16 = rem & 7;
            const short* src = (pl == 0) ? th0 : ((pl == 1) ? th1 : th2);
            uint4 v = *(const uint4*)(src + (size_t)(cb + col) * 256 + kt * 64 + c16 * 8);
            *(uint4*)&Bp[pl][OIDX(col, c16)] = v;
        }
        __syncthreads();
        #pragma unroll
        for (int ks = 0; ks < 2; ++ks) {
            bf16x8 b0[2], b1[2], b2[2];
            #pragma unroll
            for (int nf = 0; nf < 2; ++nf) {
                int brow = wave * 32 + nf * 16 + lm;
                int bix = OIDX(brow, ks * 4 + kg);
                b0[nf] = *(const bf16x8*)&Bp[0][bix];
                b1[nf] = *(const bf16x8*)&Bp[1][bix];
                b2[nf] = *(const bf16x8*)&Bp[2][bix];
            }
            #pragma unroll
            for (int mf = 0; mf < 4; ++mf) {
                int ar = mf * 16 + lm;
                int aix = OIDX(ar, ks * 4 + kg);
                bf16x8 a0 = *(const bf16x8*)&Ap[0][aix];
                bf16x8 a1 = *(const bf16x8*)&Ap[1][aix];
                bf16x8 a2 = *(const bf16x8*)&Ap[2][aix];
                #pragma unroll
                for (int nf = 0; nf < 2; ++nf) {
                    acc[mf][nf] = __builtin_amdgcn_mfma_f32_16x16x32_bf16(a0, b0[nf], acc[mf][nf], 0, 0, 0);
                    acc[mf][nf] = __builtin_amdgcn_mfma_f32_16x16x32_bf16(a0, b1[nf], acc[mf][nf], 0, 0, 0);
                    acc[mf][nf] = __builtin_amdgcn_mfma_f32_16x16x32_bf16(a1, b0[nf], acc[mf][nf], 0, 0, 0);
                    acc[mf][nf] = __builtin_amdgcn_mfma_f32_16x16x32_bf16(a1, b1[nf], acc[mf][nf], 0, 0, 0);
                    acc[mf][nf] = __builtin_amdgcn_mfma_f32_16x16x32_bf16(a0, b2[nf], acc[mf][nf], 0, 0, 0);
                    acc[mf][nf] = __builtin_amdgcn_mfma_f32_16x16x32_bf16(a2, b0[nf], acc[mf][nf], 0, 0, 0);
                }
            }
        }
        __syncthreads();
    }
    #pragma unroll
    for (int mf = 0; mf < 4; ++mf) {
        int grow = rb + mf * 16 + kg * 4;
        #pragma unroll
        for (int nf = 0; nf < 2; ++nf) {
            int gcol = cb + wave * 32 + nf * 16 + lm;
            #pragma unroll
            for (int r = 0; r < 4; ++r)
                TX[(size_t)(grow + r) * 256 + gcol] = acc[mf][nf][r];
        }
    }
}

// ---------------- q[row] = dot(X[row], TX[row]) ----------------
__global__ __launch_bounds__(256) void q_kernel(const float* __restrict__ X,
                                                const float* __restrict__ TX,
                                                float* __restrict__ q) {
    int row = blockIdx.x * 4 + (threadIdx.x >> 6);
    int lane = threadIdx.x & 63;
    float4 a = *(const float4*)(X + (size_t)row * 256 + lane * 4);
    float4 b = *(const float4*)(TX + (size_t)row * 256 + lane * 4);
    float d = a.x * b.x + a.y * b.y + a.z * b.z + a.w * b.w;
    #pragma unroll
    for (int off = 32; off > 0; off >>= 1) d += __shfl_down(d, off, 64);
    if (lane == 0) q[row] = d;
}

// ------- fused logits + column(f) softmax -> bf16 weights (single plane) -------
__global__ __launch_bounds__(256) void logits_fused_kernel(const float* __restrict__ x,
                                                           const float* __restrict__ txg,
                                                           const float* __restrict__ q,
                                                           const float* __restrict__ maskf,
                                                           const float* __restrict__ sm,
                                                           short* __restrict__ Whp) {
    __shared__ __align__(16) float Af[32][260];   // [k][f]
    __shared__ __align__(16) float Bp[32][68];    // [k][p]
    __shared__ __align__(16) float red[16][68];
    __shared__ float colM_s[64], colR_s[64];
    __shared__ float qf_s[256], qp_s[64];
    int tid = threadIdx.x;
    int b = blockIdx.y;
    int pb = blockIdx.x * 64;
    int tx = tid & 15, ty = tid >> 4;
    const float* Xf = x + (size_t)b * NT * ND + (size_t)NP * ND;
    const float* Txb = txg + (size_t)b * NT * ND;
    qf_s[tid] = q[b * NT + NP + tid];
    if (tid < 64) qp_s[tid] = q[b * NT + pb + tid];
    int sr = tid >> 3, sc = (tid & 7) * 4;
    float acc[16][4] = {};
    for (int kb = 0; kb < 256; kb += 32) {
        #pragma unroll
        for (int pass = 0; pass < 8; ++pass) {
            int r = sr + pass * 32;
            float4 g = *(const float4*)(Xf + (size_t)r * 256 + kb + sc);
            Af[sc + 0][r] = g.x; Af[sc + 1][r] = g.y;
            Af[sc + 2][r] = g.z; Af[sc + 3][r] = g.w;
        }
        #pragma unroll
        for (int pass = 0; pass < 2; ++pass) {
            int r = sr + pass * 32;
            float4 g = *(const float4*)(Txb + (size_t)(pb + r) * 256 + kb + sc);
            Bp[sc + 0][r] = g.x; Bp[sc + 1][r] = g.y;
            Bp[sc + 2][r] = g.z; Bp[sc + 3][r] = g.w;
        }
        __syncthreads();
        #pragma unroll
        for (int k = 0; k < 32; ++k) {
            float4 bv = *(const float4*)&Bp[k][tx * 4];
            float bj[4] = {bv.x, bv.y, bv.z, bv.w};
            #pragma unroll
            for (int s = 0; s < 4; ++s) {
                float4 av = *(const float4*)&Af[k][s * 64 + ty * 4];
                float ai[4] = {av.x, av.y, av.z, av.w};
                #pragma unroll
                for (int i = 0; i < 4; ++i)
                    #pragma unroll
                    for (int j = 0; j < 4; ++j) acc[s * 4 + i][j] += ai[i] * bj[j];
            }
        }
        __syncthreads();
    }
    float sg = 1.f / (1.f + expf(-sm[0]));
    float cc = 0.5f / (sg * 0.01f);
    #pragma unroll
    for (int s = 0; s < 4; ++s)
        #pragma unroll
        for (int i = 0; i < 4; ++i) {
            int f = s * 64 + ty * 4 + i;
            float qf = qf_s[f];
            float4 mv = *(const float4*)(maskf + (size_t)f * NP + pb + tx * 4);
            float mm[4] = {mv.x, mv.y, mv.z, mv.w};
            #pragma unroll
            for (int j = 0; j < 4; ++j) {
                float qp = qp_s[tx * 4 + j];
                float v = cc * (2.f * acc[s * 4 + i][j] - qf - qp);
                acc[s * 4 + i][j] = (mm[j] != 0.f) ? v : -1e30f;
            }
        }
    // column max over f
    float lm[4] = {-1e30f, -1e30f, -1e30f, -1e30f};
    #pragma unroll
    for (int r = 0; r < 16; ++r)
        #pragma unroll
        for (int j = 0; j < 4; ++j) lm[j] = fmaxf(lm[j], acc[r][j]);
    __syncthreads();
    *(float4*)&red[ty][tx * 4] = make_float4(lm[0], lm[1], lm[2], lm[3]);
    __syncthreads();
    if (tid < 64) {
        float m = -1e30f;
        #pragma unroll
        for (int t = 0; t < 16; ++t) m = fmaxf(m, red[t][tid]);
        colM_s[tid] = m;
    }
    __syncthreads();
    // column sum of exp
    float ls[4] = {0.f, 0.f, 0.f, 0.f};
    #pragma unroll
    for (int j = 0; j < 4; ++j) {
        float m = colM_s[tx * 4 + j];
        #pragma unroll
        for (int r = 0; r < 16; ++r) ls[j] += __expf(acc[r][j] - m);
    }
    __syncthreads();
    *(float4*)&red[ty][tx * 4] = make_float4(ls[0], ls[1], ls[2], ls[3]);
    __syncthreads();
    if (tid < 64) {
        float ssum = 0.f;
        #pragma unroll
        for (int t = 0; t < 16; ++t) ssum += red[t][tid];
        colR_s[tid] = (colM_s[tid] <= -1e29f) ? 0.f : 1.f / ssum;
    }
    __syncthreads();
    // normalized weights -> bf16 (single plane)
    #pragma unroll
    for (int s = 0; s < 4; ++s)
        #pragma unroll
        for (int i = 0; i < 4; ++i) {
            int f = s * 64 + ty * 4 + i;
            short4 ph;
            #pragma unroll
            for (int j = 0; j < 4; ++j) {
                float m = colM_s[tx * 4 + j];
                float r = colR_s[tx * 4 + j];
                float wv = __expf(acc[s * 4 + i][j] - m) * r;
                ((short*)&ph)[j] = f2bf(wv);
            }
            size_t off = (size_t)b * NF * NP + (size_t)f * NP + pb + tx * 4;
            *(short4*)(Whp + off) = ph;
        }
}

// ------- y transpose + bf16: yT[b][d][p] -------
__global__ __launch_bounds__(256) void ytr_kernel(const float* __restrict__ y,
                                                  short* __restrict__ Yh) {
    __shared__ __align__(16) float T[64][65];
    int b = blockIdx.z;
    int p0 = blockIdx.x * 64, d0 = blockIdx.y * 64;
    int tid = threadIdx.x;
    int r = tid >> 4, c4 = (tid & 15) * 4;
    const float* yb = y + ((size_t)b * NP + p0) * ND + d0;
    #pragma unroll
    for (int pass = 0; pass < 4; ++pass) {
        int row = pass * 16 + r;
        *(float4*)&T[row][c4] = *(const float4*)(yb + (size_t)row * ND + c4);
    }
    __syncthreads();
    short* oh = Yh + ((size_t)b * ND + d0) * NP + p0;
    #pragma unroll
    for (int pass = 0; pass < 4; ++pass) {
        int dr = pass * 16 + r;
        short4 hh;
        hh.x = f2bf(T[c4 + 0][dr]);
        hh.y = f2bf(T[c4 + 1][dr]);
        hh.z = f2bf(T[c4 + 2][dr]);
        hh.w = f2bf(T[c4 + 3][dr]);
        *(short4*)(oh + (size_t)dr * NP + c4) = hh;
    }
}

// ------- out[b] = W(256x1024) @ y(1024x256), single bf16 product MFMA -------
// 64x64 tile, BK=64, 4 waves (2x2 of 32x32), XOR-swizzled LDS, grid (4,4,64)
__global__ __launch_bounds__(256, 4) void out_mfma64_kernel(const short* __restrict__ Whp,
                                                            const short* __restrict__ Yhp,
                                                            float* __restrict__ out) {
    __shared__ __align__(16) short Ah[64 * 64];
    __shared__ __align__(16) short Bh[64 * 64];
    int tid = threadIdx.x;
    int b = blockIdx.z;
    int db = blockIdx.x * 64, fb = blockIdx.y * 64;
    int l = tid & 63, wave = tid >> 6;
    int wr = wave >> 1, wc = wave & 1;
    int lm = l & 15, kg = l >> 4;
    int srow = tid >> 2, sc16 = tid & 3;
    const short* gA = Whp + ((size_t)b * NF + fb) * NP;
    const short* gB = Yhp + ((size_t)b * ND + db) * NP;
    uint4 ra[2], rbv[2];
#define OLOAD(kt) do { \
    _Pragma("unroll") for (int p_ = 0; p_ < 2; ++p_) { \
        size_t go = (size_t)srow * NP + (size_t)(kt) * 64 + (sc16 + p_ * 4) * 8; \
        ra[p_]  = *(const uint4*)(gA + go); \
        rbv[p_] = *(const uint4*)(gB + go); \
    } \
} while (0)
#define OWRITE() do { \
    _Pragma("unroll") for (int p_ = 0; p_ < 2; ++p_) { \
        int ix = OIDX(srow, sc16 + p_ * 4); \
        *(uint4*)&Ah[ix] = ra[p_]; \
        *(uint4*)&Bh[ix] = rbv[p_]; \
    } \
} while (0)
    f32x4 acc[2][2];
    #pragma unroll
    for (int i = 0; i < 2; ++i)
        #pragma unroll
        for (int j = 0; j < 2; ++j) acc[i][j] = (f32x4){0.f, 0.f, 0.f, 0.f};
    OLOAD(0);
    OWRITE();
    for (int kt = 0; kt < 16; ++kt) {
        __syncthreads();
        bool more = (kt + 1) < 16;
        if (more) OLOAD(kt + 1);
        #pragma unroll
        for (int ks = 0; ks < 2; ++ks) {
            bf16x8 a_h[2], b_h[2];
            #pragma unroll
            for (int mf = 0; mf < 2; ++mf) {
                int row = wr * 32 + mf * 16 + lm;
                a_h[mf] = *(const bf16x8*)&Ah[OIDX(row, ks * 4 + kg)];
            }
            #pragma unroll
            for (int nf = 0; nf < 2; ++nf) {
                int row = wc * 32 + nf * 16 + lm;
                b_h[nf] = *(const bf16x8*)&Bh[OIDX(row, ks * 4 + kg)];
            }
            #pragma unroll
            for (int mf = 0; mf < 2; ++mf)
                #pragma unroll
                for (int nf = 0; nf < 2; ++nf)
                    acc[mf][nf] = __builtin_amdgcn_mfma_f32_16x16x32_bf16(a_h[mf], b_h[nf], acc[mf][nf], 0, 0, 0);
        }
        if (!more) break;
        __syncthreads();
        OWRITE();
    }
#undef OLOAD
#undef OWRITE
    #pragma unroll
    for (int mf = 0; mf < 2; ++mf) {
        int grow = fb + wr * 32 + mf * 16 + kg * 4;
        #pragma unroll
        for (int nf = 0; nf < 2; ++nf) {
            int gcol = db + wc * 32 + nf * 16 + lm;
            float* op = out + ((size_t)b * NF + grow) * ND + gcol;
            #pragma unroll
            for (int r = 0; r < 4; ++r) op[(size_t)r * ND] = acc[mf][nf][r];
        }
    }
}

extern "C" void kernel_launch(void* const* d_in, const int* in_sizes, int n_in,
                              void* d_out, int out_size, void* d_ws, size_t ws_size,
                              hipStream_t stream) {
    const float* x = (const float*)d_in[0];
    const float* y = (const float*)d_in[1];
    const float* A = (const float*)d_in[2];
    const float* W = (const float*)d_in[3];
    const float* sm = (const float*)d_in[4];
    float* out = (float*)d_out;

    short* th0 = (short*)d_ws;                          //  65,536 s
    short* th1 = th0 + 65536;                           //  65,536 s
    short* th2 = th1 + 65536;                           //  65,536 s
    float* maskf = (float*)(th2 + 65536);               // 262,144 f
    float* q = maskf + NF * NP;                         //  81,920 f
    float* tx = q + NB * NT;                            // 20,971,520 f
    short* Wh = (short*)(tx + (size_t)NB * NT * ND);    // 16,777,216 s
    // tx is dead after logits_fused -> reuse for Yh
    short* Yh = (short*)tx;                             // 16,777,216 s
    // total ~114 MiB

    theta_kernel<<<dim3(4, 4), 256, 0, stream>>>(W, th0, th1, th2);
    mask_kernel<<<dim3(256), 256, 0, stream>>>(A, maskf);
    txmfma_kernel<<<dim3(2, 1280), 256, 0, stream>>>(x, th0, th1, th2, tx);
    q_kernel<<<dim3(81920 / 4), 256, 0, stream>>>(x, tx, q);
    logits_fused_kernel<<<dim3(16, 64), 256, 0, stream>>>(x, tx, q, maskf, sm, Wh);
    ytr_kernel<<<dim3(16, 4, 64), 256, 0, stream>>>(y, Yh);
    out_mfma64_kernel<<<dim3(4, 4, 64), 256, 0, stream>>>(Wh, Yh, out);
}